// Round 1
// baseline (838.024 us; speedup 1.0000x reference)
//
#include <hip/hip_runtime.h>
#include <math.h>

#define N_NODE   100000
#define N_EDGE   500000
#define IN_DIM   128
#define OUT_DIM  128
#define ATTN_DIM 64
#define N_RELTAB 401   // 2*N_REL+1
#define N_QRY    64
#define N_TAU    366

// ---------------------------------------------------------------------------
// Kernel 1: build small lookup tables
// ---------------------------------------------------------------------------
__global__ void build_tables(const int* __restrict__ q_rel,
                             const int* __restrict__ q_tau_p,
                             const float* __restrict__ rela_embed,
                             const float* __restrict__ Wr_w,
                             const float* __restrict__ Wqr_w,
                             const float* __restrict__ Wqr_b,
                             const float* __restrict__ Wtau_w,
                             const float* __restrict__ w_t1,
                             const float* __restrict__ b_t1,
                             const float* __restrict__ w_t2,
                             const float* __restrict__ b_t2,
                             float* __restrict__ rel_attn,
                             float* __restrict__ qr_attn,
                             float* __restrict__ h_tau_tab,
                             float* __restrict__ tau_attn) {
    __shared__ float srow[IN_DIM];
    const int b = blockIdx.x;
    const int t = threadIdx.x;   // 0..127

    if (b < N_TAU) {
        const int q_tau = *q_tau_p;
        const float delta = (float)(b - q_tau);
        float v = w_t1[t] * delta + b_t1[t] + sinf(w_t2[t] * delta + b_t2[t]);
        h_tau_tab[b * IN_DIM + t] = v;
        srow[t] = v;
        __syncthreads();
        if (t < ATTN_DIM) {
            float acc = 0.f;
            #pragma unroll 8
            for (int d = 0; d < IN_DIM; ++d)
                acc += srow[d] * Wtau_w[d * ATTN_DIM + t];
            tau_attn[b * ATTN_DIM + t] = acc;
        }
    } else if (b < N_TAU + N_RELTAB) {
        const int r = b - N_TAU;
        srow[t] = rela_embed[r * IN_DIM + t];
        __syncthreads();
        if (t < ATTN_DIM) {
            float acc = 0.f;
            #pragma unroll 8
            for (int d = 0; d < IN_DIM; ++d)
                acc += srow[d] * Wr_w[d * ATTN_DIM + t];
            rel_attn[r * ATTN_DIM + t] = acc;
        }
    } else {
        const int i = b - N_TAU - N_RELTAB;   // 0..63
        const int r = q_rel[i];
        srow[t] = rela_embed[r * IN_DIM + t];
        __syncthreads();
        if (t < ATTN_DIM) {
            float acc = Wqr_b[t];
            #pragma unroll 8
            for (int d = 0; d < IN_DIM; ++d)
                acc += srow[d] * Wqr_w[d * ATTN_DIM + t];
            qr_attn[i * ATTN_DIM + t] = acc;
        }
    }
}

// ---------------------------------------------------------------------------
// Kernel 2: A_node = hidden @ Ws_w   (100k x 128) @ (128 x 64)
// ---------------------------------------------------------------------------
__global__ __launch_bounds__(256) void node_attn(const float* __restrict__ hidden,
                                                 const float* __restrict__ Ws_w,
                                                 float* __restrict__ A_node) {
    const int wave = threadIdx.x >> 6;
    const int lane = threadIdx.x & 63;
    const int node = blockIdx.x * 4 + wave;
    const float* h = hidden + (size_t)node * IN_DIM;
    const float2 hv = *(const float2*)(h + 2 * lane);   // lane l holds h[2l], h[2l+1]
    float acc = 0.f;
    #pragma unroll
    for (int d = 0; d < IN_DIM; ++d) {
        float x = __shfl((d & 1) ? hv.y : hv.x, d >> 1, 64);
        acc += x * Ws_w[d * ATTN_DIM + lane];
    }
    A_node[(size_t)node * ATTN_DIM + lane] = acc;
}

// ---------------------------------------------------------------------------
// Kernel 3: per-edge attention + gated scatter-add (atomics).
// ---------------------------------------------------------------------------
__global__ __launch_bounds__(256) void edge_scatter(const int* __restrict__ edges,
                                                    const int* __restrict__ q_tau_p,
                                                    const float* __restrict__ hidden,
                                                    const float* __restrict__ rela_embed,
                                                    const float* __restrict__ A_node,
                                                    const float* __restrict__ rel_attn,
                                                    const float* __restrict__ qr_attn,
                                                    const float* __restrict__ h_tau_tab,
                                                    const float* __restrict__ tau_attn,
                                                    const float* __restrict__ w_alpha_w,
                                                    const float* __restrict__ w_alpha_b,
                                                    float* __restrict__ agg,
                                                    float* __restrict__ agg_s) {
    const int wave = threadIdx.x >> 6;
    const int lane = threadIdx.x & 63;
    const int e = blockIdx.x * 4 + wave;
    const int* ed = edges + (size_t)e * 7;
    const int r_idx = ed[0];
    const int rel   = ed[2];
    const int tau   = ed[4];
    const int sub   = ed[5];
    const int obj   = ed[6];
    const int q_tau = *q_tau_p;
    const int tidx  = (tau >= 0) ? tau : q_tau;

    float a = A_node[(size_t)sub * ATTN_DIM + lane]
            + rel_attn[rel * ATTN_DIM + lane]
            + qr_attn[r_idx * ATTN_DIM + lane]
            + tau_attn[tidx * ATTN_DIM + lane];
    a = fmaxf(a, 0.f) * w_alpha_w[lane];
    #pragma unroll
    for (int off = 32; off > 0; off >>= 1)
        a += __shfl_xor(a, off, 64);
    const float alpha = 1.f / (1.f + __expf(-(a + w_alpha_b[0])));

    const size_t hb = (size_t)sub * IN_DIM;
    const int rb = rel * IN_DIM;
    const int tb = tidx * IN_DIM;
    const float m0 = hidden[hb + lane]      + rela_embed[rb + lane]      + h_tau_tab[tb + lane];
    const float m1 = hidden[hb + 64 + lane] + rela_embed[rb + 64 + lane] + h_tau_tab[tb + 64 + lane];

    const size_t ob = (size_t)obj * OUT_DIM;
    atomicAdd(&agg[ob + lane],        alpha * m0);
    atomicAdd(&agg[ob + 64 + lane],   alpha * m1);
    atomicAdd(&agg_s[ob + lane],      (1.f - alpha) * m0);
    atomicAdd(&agg_s[ob + 64 + lane], (1.f - alpha) * m1);
}

// ---------------------------------------------------------------------------
// Kernel 4: in-place row transform  out_row <- out_row @ W  (per half).
// ---------------------------------------------------------------------------
__global__ __launch_bounds__(256) void final_gemm(float* __restrict__ out,
                                                  const float* __restrict__ W_h_w,
                                                  const float* __restrict__ W_h_s_w) {
    const int half = blockIdx.x & 1;
    const int tile = blockIdx.x >> 1;          // 0 .. 3124
    const int row0 = tile * 32;
    float* buf = out + (size_t)half * N_NODE * OUT_DIM;
    const float* __restrict__ W = half ? W_h_s_w : W_h_w;

    __shared__ float lds[32 * 132];
    for (int i = threadIdx.x; i < 32 * 32; i += 256) {
        const int r = i >> 5, c4 = (i & 31) << 2;
        *(float4*)&lds[r * 132 + c4] = *(const float4*)&buf[(size_t)(row0 + r) * 128 + c4];
    }
    __syncthreads();

    const int cl = threadIdx.x & 63;
    const int rg = threadIdx.x >> 6;           // 0..3
    float acc0[8] = {0,0,0,0,0,0,0,0};
    float acc1[8] = {0,0,0,0,0,0,0,0};

    for (int k = 0; k < 128; k += 4) {
        float wA[4], wB[4];
        #pragma unroll
        for (int j = 0; j < 4; ++j) {
            wA[j] = W[(k + j) * 128 + cl];
            wB[j] = W[(k + j) * 128 + cl + 64];
        }
        #pragma unroll
        for (int r = 0; r < 8; ++r) {
            const float4 v = *(const float4*)&lds[(rg * 8 + r) * 132 + k];
            acc0[r] += v.x * wA[0] + v.y * wA[1] + v.z * wA[2] + v.w * wA[3];
            acc1[r] += v.x * wB[0] + v.y * wB[1] + v.z * wB[2] + v.w * wB[3];
        }
    }

    #pragma unroll
    for (int r = 0; r < 8; ++r) {
        buf[(size_t)(row0 + rg * 8 + r) * 128 + cl]      = acc0[r];
        buf[(size_t)(row0 + rg * 8 + r) * 128 + cl + 64] = acc1[r];
    }
}

// ---------------------------------------------------------------------------
extern "C" void kernel_launch(void* const* d_in, const int* in_sizes, int n_in,
                              void* d_out, int out_size, void* d_ws, size_t ws_size,
                              hipStream_t stream) {
    const int*   q_rel      = (const int*)d_in[1];
    const int*   q_tau_p    = (const int*)d_in[2];
    const float* hidden     = (const float*)d_in[3];
    const int*   edges      = (const int*)d_in[4];
    const float* rela_embed = (const float*)d_in[7];
    const float* Ws_w       = (const float*)d_in[8];
    const float* Wr_w       = (const float*)d_in[9];
    const float* Wqr_w      = (const float*)d_in[10];
    const float* Wqr_b      = (const float*)d_in[11];
    const float* Wtau_w     = (const float*)d_in[12];
    const float* w_alpha_w  = (const float*)d_in[13];
    const float* w_alpha_b  = (const float*)d_in[14];
    const float* W_h_w      = (const float*)d_in[15];
    const float* W_h_s_w    = (const float*)d_in[16];
    const float* w_t1       = (const float*)d_in[17];
    const float* b_t1       = (const float*)d_in[18];
    const float* w_t2       = (const float*)d_in[19];
    const float* b_t2       = (const float*)d_in[20];

    float* ws       = (float*)d_ws;
    float* A_node   = ws;                                   // 100000*64
    float* rel_attn = A_node + (size_t)N_NODE * ATTN_DIM;   // 401*64
    float* qr_attn  = rel_attn + N_RELTAB * ATTN_DIM;       // 64*64
    float* h_tau    = qr_attn + N_QRY * ATTN_DIM;           // 366*128
    float* tau_attn = h_tau + N_TAU * IN_DIM;               // 366*64

    float* agg   = (float*)d_out;
    float* agg_s = (float*)d_out + (size_t)N_NODE * OUT_DIM;

    hipMemsetAsync(d_out, 0, (size_t)2 * N_NODE * OUT_DIM * sizeof(float), stream);

    build_tables<<<dim3(N_TAU + N_RELTAB + N_QRY), dim3(128), 0, stream>>>(
        q_rel, q_tau_p, rela_embed, Wr_w, Wqr_w, Wqr_b, Wtau_w,
        w_t1, b_t1, w_t2, b_t2, rel_attn, qr_attn, h_tau, tau_attn);

    node_attn<<<dim3(N_NODE / 4), dim3(256), 0, stream>>>(hidden, Ws_w, A_node);

    edge_scatter<<<dim3(N_EDGE / 4), dim3(256), 0, stream>>>(
        edges, q_tau_p, hidden, rela_embed, A_node, rel_attn, qr_attn,
        h_tau, tau_attn, w_alpha_w, w_alpha_b, agg, agg_s);

    final_gemm<<<dim3(2 * (N_NODE / 32)), dim3(256), 0, stream>>>(
        (float*)d_out, W_h_w, W_h_s_w);
}